// Round 4
// baseline (142.203 us; speedup 1.0000x reference)
//
#include <hip/hip_runtime.h>
#include <hip/hip_bf16.h>
#include <stdint.h>

typedef __attribute__((ext_vector_type(8))) __bf16 bf16x8;
typedef __attribute__((ext_vector_type(8))) short  short8;
typedef __attribute__((ext_vector_type(4))) float  f32x4;

#define MFMA16(a, b, c) __builtin_amdgcn_mfma_f32_16x16x32_bf16((a), (b), (c), 0, 0, 0)

__device__ __forceinline__ unsigned short f32_bf16(float f) {
  union { float f; unsigned u; } v; v.f = f;
  unsigned r = v.u + 0x7FFFu + ((v.u >> 16) & 1u);
  return (unsigned short)(r >> 16);
}

// async global->LDS, 16B per lane; LDS dest is wave-uniform base (+lane*16 by HW)
__device__ __forceinline__ void gload16(const unsigned short* g, unsigned short* l) {
  __builtin_amdgcn_global_load_lds(
      (const __attribute__((address_space(1))) unsigned int*)(g),
      (__attribute__((address_space(3))) unsigned int*)(l), 16, 0, 0);
}

// ---------------- fp32 -> bf16 convert (all 3 inputs, one launch) ----------------
__global__ void cvt3_kernel(const float* __restrict__ a, int na4,
                            const float* __restrict__ b, int nb4,
                            const float* __restrict__ c, int nc4,
                            unsigned short* __restrict__ oa,
                            unsigned short* __restrict__ ob,
                            unsigned short* __restrict__ oc) {
  int total = na4 + nb4 + nc4;
  for (int i = blockIdx.x * blockDim.x + threadIdx.x; i < total; i += gridDim.x * blockDim.x) {
    const float* src; unsigned short* dst; int j = i;
    if (j < na4) { src = a; dst = oa; }
    else if (j - na4 < nb4) { j -= na4; src = b; dst = ob; }
    else { j -= na4 + nb4; src = c; dst = oc; }
    float4 v = reinterpret_cast<const float4*>(src)[j];
    ushort4 o4;
    o4.x = f32_bf16(v.x); o4.y = f32_bf16(v.y);
    o4.z = f32_bf16(v.z); o4.w = f32_bf16(v.w);
    reinterpret_cast<ushort4*>(dst)[j] = o4;
  }
}

// ---------------- bf16 GEMM, C = A * B^T (m97 structure) ----------------
// MODE 0: Q,K -> [bh][s][64] bf16 (Q scaled log2e/8), V -> transposed [bh][64][s];
//         LDS-staged coalesced epilogue stores (dwordx4).
// MODE 1: fp32 row-major [M][N] direct stores.
template <int MODE>
__global__ __launch_bounds__(256) void gemm_bt(const unsigned short* __restrict__ A,
                                               const unsigned short* __restrict__ Bm,
                                               void* __restrict__ Cout,
                                               int M, int N, int K) {
  __shared__ unsigned short As[128 * 32];
  __shared__ unsigned short Bs[128 * 32];
  __shared__ unsigned short Es[2 * 64 * 64];  // epilogue staging for waves 2,3
  const int tid  = threadIdx.x;
  const int lane = tid & 63;
  const int wid  = tid >> 6;
  const int wr   = wid >> 1, wc = wid & 1;
  const int l16  = lane & 15, lh = lane >> 4;
  const int m0   = blockIdx.y * 128;
  const int n0   = blockIdx.x * 128;

  f32x4 acc[4][4];
#pragma unroll
  for (int mi = 0; mi < 4; ++mi)
#pragma unroll
    for (int ni = 0; ni < 4; ++ni) acc[mi][ni] = 0.f;

  const int c0 = tid, c1 = 256 + tid;
  const unsigned short* a0 = A + (size_t)(m0 + (c0 >> 2)) * K + (c0 & 3) * 8;
  const unsigned short* a1 = A + (size_t)(m0 + (c1 >> 2)) * K + (c1 & 3) * 8;
  const unsigned short* b0 = Bm + (size_t)(n0 + (c0 >> 2)) * K + (c0 & 3) * 8;
  const unsigned short* b1 = Bm + (size_t)(n0 + (c1 >> 2)) * K + (c1 & 3) * 8;
  const int d0 = wid * 64 * 8;
  const int d1 = (256 + wid * 64) * 8;

  for (int k0 = 0; k0 < K; k0 += 32) {
    __syncthreads();
    gload16(a0 + k0, As + d0);
    gload16(a1 + k0, As + d1);
    gload16(b0 + k0, Bs + d0);
    gload16(b1 + k0, Bs + d1);
    __syncthreads();
    bf16x8 af[4], bfr[4];
#pragma unroll
    for (int i = 0; i < 4; ++i) {
      af[i]  = *(const bf16x8*)(As + (wr * 64 + i * 16 + l16) * 32 + lh * 8);
      bfr[i] = *(const bf16x8*)(Bs + (wc * 64 + i * 16 + l16) * 32 + lh * 8);
    }
#pragma unroll
    for (int mi = 0; mi < 4; ++mi)
#pragma unroll
      for (int ni = 0; ni < 4; ++ni)
        acc[mi][ni] = MFMA16(af[mi], bfr[ni], acc[mi][ni]);
  }

  if (MODE == 0) {
    __syncthreads();  // all waves done reading As/Bs before reuse as staging
    unsigned short* Ep = (wid == 0) ? As : (wid == 1) ? Bs : Es + (wid - 2) * 4096;
    const int gn0 = n0 + wc * 64;
    const int cc  = gn0 >> 10;
    const int hh2 = (gn0 & 1023) >> 6;
    const int gm0 = m0 + wr * 64;
    const int bb2 = gm0 >> 11;
    const int ss0 = gm0 & 2047;
    const int bh2 = bb2 * 16 + hh2;
    unsigned short* qkv = (unsigned short*)Cout;

    if (cc < 2) {
      // LDS [ss][dk], col XOR'd by lh to dodge banks; scalar writes, b128 reads
      const float qsc = (cc == 0) ? 0.18033688f : 1.0f;  // 1/sqrt(64)*log2(e)
#pragma unroll
      for (int mi = 0; mi < 4; ++mi)
#pragma unroll
        for (int ni = 0; ni < 4; ++ni)
#pragma unroll
          for (int r = 0; r < 4; ++r) {
            int row = mi * 16 + lh * 4 + r;
            int col = (ni * 16 + l16) ^ (lh << 3);
            Ep[row * 64 + col] = f32_bf16(acc[mi][ni][r] * qsc);
          }
      unsigned short* qk = qkv + (((size_t)cc * 32 + bh2) * 2048 + ss0) * 64;
#pragma unroll
      for (int it = 0; it < 8; ++it) {
        int ci = it * 64 + lane;
        int row = ci >> 3, c = ci & 7;
        short8 vv = *(const short8*)(Ep + row * 64 + ((c ^ ((row >> 2) & 3)) * 8));
        *(short8*)(qk + (size_t)row * 64 + c * 8) = vv;
      }
    } else {
      // V: LDS [dk][ss], packed b64 writes (cvt_pk), b128 row reads
#pragma unroll
      for (int mi = 0; mi < 4; ++mi)
#pragma unroll
        for (int ni = 0; ni < 4; ++ni) {
          int dk = ni * 16 + l16;
          int ssl = mi * 16 + lh * 4;
          unsigned lo, hi;
          asm("v_cvt_pk_bf16_f32 %0, %1, %2" : "=v"(lo) : "v"(acc[mi][ni][0]), "v"(acc[mi][ni][1]));
          asm("v_cvt_pk_bf16_f32 %0, %1, %2" : "=v"(hi) : "v"(acc[mi][ni][2]), "v"(acc[mi][ni][3]));
          int off = dk * 64 + (ssl ^ ((dk & 7) << 3));
          *(uint2*)(Ep + off) = make_uint2(lo, hi);
        }
      unsigned short* vt = qkv + (size_t)8388608 + (size_t)bh2 * 64 * 2048 + ss0;
#pragma unroll
      for (int it = 0; it < 8; ++it) {
        int ci = it * 64 + lane;
        int dk = ci >> 3, c = ci & 7;
        short8 vv = *(const short8*)(Ep + dk * 64 + ((c ^ (dk & 7)) * 8));
        *(short8*)(vt + (size_t)dk * 2048 + c * 8) = vv;
      }
    }
  } else {
    float* C = (float*)Cout;
#pragma unroll
    for (int mi = 0; mi < 4; ++mi)
#pragma unroll
      for (int ni = 0; ni < 4; ++ni)
#pragma unroll
        for (int r = 0; r < 4; ++r) {
          int gm = m0 + wr * 64 + mi * 16 + lh * 4 + r;
          int gn = n0 + wc * 64 + ni * 16 + l16;
          C[(size_t)gm * N + gn] = acc[mi][ni][r];
        }
  }
}

// ---------------- causal flash attention (swapped-QK^T) ----------------
// Q: [bh][2048][64] (prescaled log2e/8), K: [bh][2048][64], Vt: [bh][64][2048].
// 4 waves x 32 q-rows = 128 q-rows/block, KVBLK=64. S^T = mfma(K,Q): lane l16
// owns q-rows (rg*16+l16); P packed to LDS via cvt_pk b64; defer-max, exp2.
__global__ __launch_bounds__(256) void attn_kernel(const unsigned short* __restrict__ Qg,
                                                   const unsigned short* __restrict__ Kg,
                                                   const unsigned short* __restrict__ Vtg,
                                                   unsigned short* __restrict__ Og) {
  __shared__ unsigned short Ks[2][64 * 64];
  __shared__ unsigned short Vs[2][64 * 64];
  __shared__ unsigned short Pl[4][32 * 64];

  const int tid  = threadIdx.x;
  const int lane = tid & 63;
  const int w    = tid >> 6;
  const int l16  = lane & 15, lh = lane >> 4;
  const int qt   = 15 - (blockIdx.x >> 5);  // LPT: heaviest q-blocks first
  const int bh   = blockIdx.x & 31;
  const int bb   = bh >> 4, hh = bh & 15;
  const int qb   = qt * 128;
  const int wqb  = qb + w * 32;

  const unsigned short* Qh = Qg + (size_t)bh * (2048 * 64);
  const unsigned short* Kh = Kg + (size_t)bh * (2048 * 64);
  const unsigned short* Vh = Vtg + (size_t)bh * (64 * 2048);

  bf16x8 qf[2][2];
#pragma unroll
  for (int rg = 0; rg < 2; ++rg)
#pragma unroll
    for (int h2 = 0; h2 < 2; ++h2)
      qf[rg][h2] = *(const bf16x8*)(Qh + (size_t)(wqb + rg * 16 + l16) * 64 + h2 * 32 + lh * 8);

  float mreg[2] = {0.f, 0.f};   // defer-max baseline (scores ~0); slow path handles growth
  float ll[2]   = {0.f, 0.f};
  f32x4 o[2][4];
#pragma unroll
  for (int rg = 0; rg < 2; ++rg)
#pragma unroll
    for (int f = 0; f < 4; ++f) o[rg][f] = 0.f;

  // staging: LDS slot sigma holds chunk (r=sigma>>3, h=(sigma&7)^(r&7)) - involutive
  const int sA = tid, sB = tid + 256;
  const int rA = sA >> 3, hA = (sA & 7) ^ (rA & 7);
  const int rB = sB >> 3, hB = (sB & 7) ^ (rB & 7);
  const unsigned short* kSrcA = Kh + rA * 64 + hA * 8;
  const unsigned short* kSrcB = Kh + rB * 64 + hB * 8;
  const unsigned short* vSrcA = Vh + (size_t)rA * 2048 + hA * 8;
  const unsigned short* vSrcB = Vh + (size_t)rB * 2048 + hB * 8;
  const int ldsA = w * 64 * 8;
  const int ldsB = (256 + w * 64) * 8;

  const int sw = l16 & 7;
  const int ntiles = 2 * qt + 2;

  gload16(kSrcA, &Ks[0][ldsA]);
  gload16(kSrcB, &Ks[0][ldsB]);
  gload16(vSrcA, &Vs[0][ldsA]);
  gload16(vSrcB, &Vs[0][ldsB]);
  __syncthreads();

  for (int t = 0; t < ntiles; ++t) {
    const int kv0 = t * 64;
    const int cur = t & 1;
    if (t + 1 < ntiles) {
      const int nk = kv0 + 64;
      gload16(kSrcA + (size_t)nk * 64, &Ks[cur ^ 1][ldsA]);
      gload16(kSrcB + (size_t)nk * 64, &Ks[cur ^ 1][ldsB]);
      gload16(vSrcA + nk, &Vs[cur ^ 1][ldsA]);
      gload16(vSrcB + nk, &Vs[cur ^ 1][ldsB]);
    }

    if (kv0 <= wqb + 31) {  // wave-uniform skip of fully-masked tiles
      const unsigned short* Kb = Ks[cur];
      const unsigned short* Vb = Vs[cur];

      // S^T[tt][rg]: row = kv (lh*4+r), col = q-row (l16)
      f32x4 st[4][2];
#pragma unroll
      for (int tt = 0; tt < 4; ++tt) {
        const unsigned short* krow = Kb + (tt * 16 + l16) * 64;
        bf16x8 kf0 = *(const bf16x8*)(krow + ((lh ^ sw) * 8));
        bf16x8 kf1 = *(const bf16x8*)(krow + (((lh + 4) ^ sw) * 8));
#pragma unroll
        for (int rg = 0; rg < 2; ++rg) {
          f32x4 a = {0.f, 0.f, 0.f, 0.f};
          a = MFMA16(kf0, qf[rg][0], a);
          a = MFMA16(kf1, qf[rg][1], a);
          st[tt][rg] = a;
        }
      }

      if (kv0 + 63 > wqb) {  // causal mask
#pragma unroll
        for (int tt = 0; tt < 4; ++tt)
#pragma unroll
          for (int rg = 0; rg < 2; ++rg) {
            int qrow = wqb + rg * 16 + l16;
            int kvb = kv0 + tt * 16 + lh * 4;
#pragma unroll
            for (int r = 0; r < 4; ++r)
              if (kvb + r > qrow) st[tt][rg][r] = -__builtin_inff();
          }
      }

      // defer-max
      float pm[2];
#pragma unroll
      for (int rg = 0; rg < 2; ++rg) {
        float t0 = fmaxf(fmaxf(st[0][rg][0], st[0][rg][1]), fmaxf(st[0][rg][2], st[0][rg][3]));
#pragma unroll
        for (int tt = 1; tt < 4; ++tt) {
          t0 = fmaxf(t0, fmaxf(fmaxf(st[tt][rg][0], st[tt][rg][1]),
                               fmaxf(st[tt][rg][2], st[tt][rg][3])));
        }
        pm[rg] = t0;
      }
      int ok = (pm[0] <= mreg[0] + 8.f) && (pm[1] <= mreg[1] + 8.f);
      if (!__all(ok)) {  // slow path: reduce + rescale (rare for this data)
        float er[2];
#pragma unroll
        for (int rg = 0; rg < 2; ++rg) {
          float t0 = pm[rg];
          t0 = fmaxf(t0, __shfl_xor(t0, 16));
          t0 = fmaxf(t0, __shfl_xor(t0, 32));
          float mn = fmaxf(mreg[rg], t0);
          er[rg] = exp2f(mreg[rg] - mn);
          mreg[rg] = mn;
          ll[rg] *= er[rg];
        }
#pragma unroll
        for (int rg = 0; rg < 2; ++rg)
#pragma unroll
          for (int r = 0; r < 4; ++r) {
            float e = __shfl(er[rg], lh * 4 + r);
#pragma unroll
            for (int f = 0; f < 4; ++f) o[rg][f][r] *= e;
          }
      }

      // P = exp2(st - m) -> packed bf16 b64 LDS writes; accumulate row sums
      unsigned short* Pw = Pl[w];
#pragma unroll
      for (int rg = 0; rg < 2; ++rg) {
        int rho = rg * 16 + l16;
        int rbase = rho * 64;
        float ps = 0.f;
#pragma unroll
        for (int tt = 0; tt < 4; ++tt) {
          float p0 = exp2f(st[tt][rg][0] - mreg[rg]);
          float p1 = exp2f(st[tt][rg][1] - mreg[rg]);
          float p2 = exp2f(st[tt][rg][2] - mreg[rg]);
          float p3 = exp2f(st[tt][rg][3] - mreg[rg]);
          ps += (p0 + p1) + (p2 + p3);
          unsigned lo, hi;
          asm("v_cvt_pk_bf16_f32 %0, %1, %2" : "=v"(lo) : "v"(p0), "v"(p1));
          asm("v_cvt_pk_bf16_f32 %0, %1, %2" : "=v"(hi) : "v"(p2), "v"(p3));
          int c8 = tt * 2 + (lh >> 1);
          int off = rbase + ((c8 ^ sw) << 3) + (lh & 1) * 4;
          *(uint2*)(Pw + off) = make_uint2(lo, hi);
        }
        float rs = ps;
        rs += __shfl_xor(rs, 16);
        rs += __shfl_xor(rs, 32);
        ll[rg] += rs;
      }

      // PV: O[rg][f] col=d, row=q
#pragma unroll
      for (int rg = 0; rg < 2; ++rg) {
        int rbase = (rg * 16 + l16) * 64;
        bf16x8 pf0 = *(const bf16x8*)(Pw + rbase + ((lh ^ sw) * 8));
        bf16x8 pf1 = *(const bf16x8*)(Pw + rbase + (((lh + 4) ^ sw) * 8));
#pragma unroll
        for (int f = 0; f < 4; ++f) {
          const unsigned short* vrow = Vb + (f * 16 + l16) * 64;
          bf16x8 vf0 = *(const bf16x8*)(vrow + ((lh ^ sw) * 8));
          bf16x8 vf1 = *(const bf16x8*)(vrow + (((lh + 4) ^ sw) * 8));
          o[rg][f] = MFMA16(pf0, vf0, o[rg][f]);
          o[rg][f] = MFMA16(pf1, vf1, o[rg][f]);
        }
      }
    }
    __syncthreads();
  }

  unsigned short* op = Og + (size_t)bb * 2048 * 1024 + (size_t)hh * 64;
#pragma unroll
  for (int rg = 0; rg < 2; ++rg)
#pragma unroll
    for (int r = 0; r < 4; ++r) {
      float linv = 1.f / __shfl(ll[rg], lh * 4 + r);
      int row = wqb + rg * 16 + lh * 4 + r;
#pragma unroll
      for (int f = 0; f < 4; ++f)
        op[(size_t)row * 1024 + f * 16 + l16] = f32_bf16(o[rg][f][r] * linv);
    }
}

extern "C" void kernel_launch(void* const* d_in, const int* in_sizes, int n_in,
                              void* d_out, int out_size, void* d_ws, size_t ws_size,
                              hipStream_t stream) {
  const float* x    = (const float*)d_in[0];
  const float* Wqkv = (const float*)d_in[1];
  const float* Wout = (const float*)d_in[2];
  float* out = (float*)d_out;

  char* ws = (char*)d_ws;
  unsigned short* xb  = (unsigned short*)(ws);                              // 8 MB
  unsigned short* wqb = (unsigned short*)(ws + (size_t)8 * 1024 * 1024);    // 6 MB
  unsigned short* wob = (unsigned short*)(ws + (size_t)14 * 1024 * 1024);   // 2 MB
  unsigned short* qkv = (unsigned short*)(ws + (size_t)16 * 1024 * 1024);   // 24 MB
  unsigned short* att = (unsigned short*)(ws + (size_t)40 * 1024 * 1024);   // 8 MB

  cvt3_kernel<<<2048, 256, 0, stream>>>(x, 4194304 / 4, Wqkv, 3145728 / 4,
                                        Wout, 1048576 / 4, xb, wqb, wob);

  // QKV projection -> Q,K [bh][s][dk] (Q in exp2-space scale); V^T [bh][dk][s]
  gemm_bt<0><<<dim3(24, 32), 256, 0, stream>>>(xb, wqb, (void*)qkv, 4096, 3072, 1024);

  const unsigned short* Qp  = qkv;
  const unsigned short* Kp  = qkv + 4194304;
  const unsigned short* Vtp = qkv + 8388608;
  attn_kernel<<<512, 256, 0, stream>>>(Qp, Kp, Vtp, att);

  // output projection -> fp32 out
  gemm_bt<1><<<dim3(8, 32), 256, 0, stream>>>(att, wob, (void*)out, 4096, 1024, 1024);
}

// Round 5
// 126.311 us; speedup vs baseline: 1.1258x; 1.1258x over previous
//
#include <hip/hip_runtime.h>
#include <hip/hip_bf16.h>
#include <stdint.h>

typedef __attribute__((ext_vector_type(8))) __bf16 bf16x8;
typedef __attribute__((ext_vector_type(8))) short  short8;
typedef __attribute__((ext_vector_type(4))) float  f32x4;

#define MFMA16(a, b, c) __builtin_amdgcn_mfma_f32_16x16x32_bf16((a), (b), (c), 0, 0, 0)

__device__ __forceinline__ unsigned short f32_bf16(float f) {
  union { float f; unsigned u; } v; v.f = f;
  unsigned r = v.u + 0x7FFFu + ((v.u >> 16) & 1u);
  return (unsigned short)(r >> 16);
}

// async global->LDS, 16B per lane; LDS dest is wave-uniform base (+lane*16 by HW)
__device__ __forceinline__ void gload16(const unsigned short* g, unsigned short* l) {
  __builtin_amdgcn_global_load_lds(
      (const __attribute__((address_space(1))) unsigned int*)(g),
      (__attribute__((address_space(3))) unsigned int*)(l), 16, 0, 0);
}

// ---------------- fp32 -> bf16 convert (all 3 inputs, one launch) ----------------
__global__ void cvt3_kernel(const float* __restrict__ a, int na4,
                            const float* __restrict__ b, int nb4,
                            const float* __restrict__ c, int nc4,
                            unsigned short* __restrict__ oa,
                            unsigned short* __restrict__ ob,
                            unsigned short* __restrict__ oc) {
  int total = na4 + nb4 + nc4;
  for (int i = blockIdx.x * blockDim.x + threadIdx.x; i < total; i += gridDim.x * blockDim.x) {
    const float* src; unsigned short* dst; int j = i;
    if (j < na4) { src = a; dst = oa; }
    else if (j - na4 < nb4) { j -= na4; src = b; dst = ob; }
    else { j -= na4 + nb4; src = c; dst = oc; }
    float4 v = reinterpret_cast<const float4*>(src)[j];
    ushort4 o4;
    o4.x = f32_bf16(v.x); o4.y = f32_bf16(v.y);
    o4.z = f32_bf16(v.z); o4.w = f32_bf16(v.w);
    reinterpret_cast<ushort4*>(dst)[j] = o4;
  }
}

// ---------------- bf16 GEMM, C = A * B^T (m97 structure) ----------------
// MODE 0: Q,K -> [bh][s][64] bf16 (Q scaled log2e/8), V -> transposed [bh][64][s];
//         LDS-staged coalesced epilogue stores (dwordx4).
// MODE 1: fp32 row-major [M][N] direct stores.
template <int MODE>
__global__ __launch_bounds__(256) void gemm_bt(const unsigned short* __restrict__ A,
                                               const unsigned short* __restrict__ Bm,
                                               void* __restrict__ Cout,
                                               int M, int N, int K) {
  __shared__ unsigned short As[128 * 32];
  __shared__ unsigned short Bs[128 * 32];
  __shared__ unsigned short Es[2 * 64 * 64];  // epilogue staging for waves 2,3
  const int tid  = threadIdx.x;
  const int lane = tid & 63;
  const int wid  = tid >> 6;
  const int wr   = wid >> 1, wc = wid & 1;
  const int l16  = lane & 15, lh = lane >> 4;
  const int m0   = blockIdx.y * 128;
  const int n0   = blockIdx.x * 128;

  f32x4 acc[4][4];
#pragma unroll
  for (int mi = 0; mi < 4; ++mi)
#pragma unroll
    for (int ni = 0; ni < 4; ++ni) acc[mi][ni] = 0.f;

  const int c0 = tid, c1 = 256 + tid;
  const unsigned short* a0 = A + (size_t)(m0 + (c0 >> 2)) * K + (c0 & 3) * 8;
  const unsigned short* a1 = A + (size_t)(m0 + (c1 >> 2)) * K + (c1 & 3) * 8;
  const unsigned short* b0 = Bm + (size_t)(n0 + (c0 >> 2)) * K + (c0 & 3) * 8;
  const unsigned short* b1 = Bm + (size_t)(n0 + (c1 >> 2)) * K + (c1 & 3) * 8;
  const int d0 = wid * 64 * 8;
  const int d1 = (256 + wid * 64) * 8;

  for (int k0 = 0; k0 < K; k0 += 32) {
    __syncthreads();
    gload16(a0 + k0, As + d0);
    gload16(a1 + k0, As + d1);
    gload16(b0 + k0, Bs + d0);
    gload16(b1 + k0, Bs + d1);
    __syncthreads();
    bf16x8 af[4], bfr[4];
#pragma unroll
    for (int i = 0; i < 4; ++i) {
      af[i]  = *(const bf16x8*)(As + (wr * 64 + i * 16 + l16) * 32 + lh * 8);
      bfr[i] = *(const bf16x8*)(Bs + (wc * 64 + i * 16 + l16) * 32 + lh * 8);
    }
#pragma unroll
    for (int mi = 0; mi < 4; ++mi)
#pragma unroll
      for (int ni = 0; ni < 4; ++ni)
        acc[mi][ni] = MFMA16(af[mi], bfr[ni], acc[mi][ni]);
  }

  if (MODE == 0) {
    __syncthreads();  // all waves done reading As/Bs before reuse as staging
    unsigned short* Ep = (wid == 0) ? As : (wid == 1) ? Bs : Es + (wid - 2) * 4096;
    const int gn0 = n0 + wc * 64;
    const int cc  = gn0 >> 10;
    const int hh2 = (gn0 & 1023) >> 6;
    const int gm0 = m0 + wr * 64;
    const int bb2 = gm0 >> 11;
    const int ss0 = gm0 & 2047;
    const int bh2 = bb2 * 16 + hh2;
    unsigned short* qkv = (unsigned short*)Cout;

    if (cc < 2) {
      // LDS [ss][dk], col XOR'd by lh to dodge banks; scalar writes, b128 reads
      const float qsc = (cc == 0) ? 0.18033688f : 1.0f;  // 1/sqrt(64)*log2(e)
#pragma unroll
      for (int mi = 0; mi < 4; ++mi)
#pragma unroll
        for (int ni = 0; ni < 4; ++ni)
#pragma unroll
          for (int r = 0; r < 4; ++r) {
            int row = mi * 16 + lh * 4 + r;
            int col = (ni * 16 + l16) ^ (lh << 3);
            Ep[row * 64 + col] = f32_bf16(acc[mi][ni][r] * qsc);
          }
      unsigned short* qk = qkv + (((size_t)cc * 32 + bh2) * 2048 + ss0) * 64;
#pragma unroll
      for (int it = 0; it < 8; ++it) {
        int ci = it * 64 + lane;
        int row = ci >> 3, c = ci & 7;
        short8 vv = *(const short8*)(Ep + row * 64 + ((c ^ ((row >> 2) & 3)) * 8));
        *(short8*)(qk + (size_t)row * 64 + c * 8) = vv;
      }
    } else {
      // V: LDS [dk][ss], packed b64 writes (cvt_pk), b128 row reads
#pragma unroll
      for (int mi = 0; mi < 4; ++mi)
#pragma unroll
        for (int ni = 0; ni < 4; ++ni) {
          int dk = ni * 16 + l16;
          int ssl = mi * 16 + lh * 4;
          unsigned lo, hi;
          asm("v_cvt_pk_bf16_f32 %0, %1, %2" : "=v"(lo) : "v"(acc[mi][ni][0]), "v"(acc[mi][ni][1]));
          asm("v_cvt_pk_bf16_f32 %0, %1, %2" : "=v"(hi) : "v"(acc[mi][ni][2]), "v"(acc[mi][ni][3]));
          int off = dk * 64 + (ssl ^ ((dk & 7) << 3));
          *(uint2*)(Ep + off) = make_uint2(lo, hi);
        }
      unsigned short* vt = qkv + (size_t)8388608 + (size_t)bh2 * 64 * 2048 + ss0;
#pragma unroll
      for (int it = 0; it < 8; ++it) {
        int ci = it * 64 + lane;
        int dk = ci >> 3, c = ci & 7;
        short8 vv = *(const short8*)(Ep + dk * 64 + ((c ^ (dk & 7)) * 8));
        *(short8*)(vt + (size_t)dk * 2048 + c * 8) = vv;
      }
    }
  } else {
    float* C = (float*)Cout;
#pragma unroll
    for (int mi = 0; mi < 4; ++mi)
#pragma unroll
      for (int ni = 0; ni < 4; ++ni)
#pragma unroll
        for (int r = 0; r < 4; ++r) {
          int gm = m0 + wr * 64 + mi * 16 + lh * 4 + r;
          int gn = n0 + wc * 64 + ni * 16 + l16;
          C[(size_t)gm * N + gn] = acc[mi][ni][r];
        }
  }
}

// ---------------- causal flash attention (swapped-QK^T, 64q/block) ----------------
// Q: [bh][2048][64] (prescaled log2e/8), K: [bh][2048][64], Vt: [bh][64][2048].
// 4 waves x 16 q-rows = 64 q-rows/block, 1024 blocks (round-3 parallelism),
// KVBLK=64, S^T = mfma(K,Q): lane l16 owns q-row; P packed b64; defer-max, exp2.
__global__ __launch_bounds__(256) void attn_kernel(const unsigned short* __restrict__ Qg,
                                                   const unsigned short* __restrict__ Kg,
                                                   const unsigned short* __restrict__ Vtg,
                                                   unsigned short* __restrict__ Og) {
  __shared__ unsigned short Ks[2][64 * 64];
  __shared__ unsigned short Vs[2][64 * 64];
  __shared__ unsigned short Pl[4][16 * 64];

  const int tid  = threadIdx.x;
  const int lane = tid & 63;
  const int w    = tid >> 6;
  const int l16  = lane & 15, lh = lane >> 4;
  const int qt   = 31 - (blockIdx.x >> 5);  // LPT: heaviest q-blocks first
  const int bh   = blockIdx.x & 31;
  const int bb   = bh >> 4, hh = bh & 15;
  const int qb   = qt * 64;
  const int wqb  = qb + w * 16;

  const unsigned short* Qh = Qg + (size_t)bh * (2048 * 64);
  const unsigned short* Kh = Kg + (size_t)bh * (2048 * 64);
  const unsigned short* Vh = Vtg + (size_t)bh * (64 * 2048);

  bf16x8 qf[2];
#pragma unroll
  for (int h2 = 0; h2 < 2; ++h2)
    qf[h2] = *(const bf16x8*)(Qh + (size_t)(wqb + l16) * 64 + h2 * 32 + lh * 8);

  float mreg = 0.f;   // defer-max baseline (scores ~0); slow path handles growth
  float ll   = 0.f;
  f32x4 o[4];
#pragma unroll
  for (int f = 0; f < 4; ++f) o[f] = 0.f;

  // staging: LDS slot sigma holds chunk (r=sigma>>3, h=(sigma&7)^(r&7)) - involutive
  const int sA = tid, sB = tid + 256;
  const int rA = sA >> 3, hA = (sA & 7) ^ (rA & 7);
  const int rB = sB >> 3, hB = (sB & 7) ^ (rB & 7);
  const unsigned short* kSrcA = Kh + rA * 64 + hA * 8;
  const unsigned short* kSrcB = Kh + rB * 64 + hB * 8;
  const unsigned short* vSrcA = Vh + (size_t)rA * 2048 + hA * 8;
  const unsigned short* vSrcB = Vh + (size_t)rB * 2048 + hB * 8;
  const int ldsA = w * 64 * 8;
  const int ldsB = (256 + w * 64) * 8;

  const int sw = l16 & 7;
  const int ntiles = qt + 1;

  gload16(kSrcA, &Ks[0][ldsA]);
  gload16(kSrcB, &Ks[0][ldsB]);
  gload16(vSrcA, &Vs[0][ldsA]);
  gload16(vSrcB, &Vs[0][ldsB]);
  __syncthreads();

  for (int t = 0; t < ntiles; ++t) {
    const int kv0 = t * 64;
    const int cur = t & 1;
    if (t + 1 < ntiles) {
      const int nk = kv0 + 64;
      gload16(kSrcA + (size_t)nk * 64, &Ks[cur ^ 1][ldsA]);
      gload16(kSrcB + (size_t)nk * 64, &Ks[cur ^ 1][ldsB]);
      gload16(vSrcA + nk, &Vs[cur ^ 1][ldsA]);
      gload16(vSrcB + nk, &Vs[cur ^ 1][ldsB]);
    }

    if (kv0 <= wqb + 15) {  // wave-uniform skip of fully-masked tiles
      const unsigned short* Kb = Ks[cur];
      const unsigned short* Vb = Vs[cur];

      // S^T[tt]: row = kv (tt*16+lh*4+r), col = q-row (l16)
      f32x4 st[4];
#pragma unroll
      for (int tt = 0; tt < 4; ++tt) {
        const unsigned short* krow = Kb + (tt * 16 + l16) * 64;
        bf16x8 kf0 = *(const bf16x8*)(krow + ((lh ^ sw) * 8));
        bf16x8 kf1 = *(const bf16x8*)(krow + (((lh + 4) ^ sw) * 8));
        f32x4 a = {0.f, 0.f, 0.f, 0.f};
        a = MFMA16(kf0, qf[0], a);
        a = MFMA16(kf1, qf[1], a);
        st[tt] = a;
      }

      if (kv0 + 63 > wqb) {  // causal mask (diag tiles only)
        int qrow = wqb + l16;
#pragma unroll
        for (int tt = 0; tt < 4; ++tt) {
          int kvb = kv0 + tt * 16 + lh * 4;
#pragma unroll
          for (int r = 0; r < 4; ++r)
            if (kvb + r > qrow) st[tt][r] = -__builtin_inff();
        }
      }

      // defer-max: fast path has no shuffles, no rescale
      float pm = fmaxf(fmaxf(st[0][0], st[0][1]), fmaxf(st[0][2], st[0][3]));
#pragma unroll
      for (int tt = 1; tt < 4; ++tt)
        pm = fmaxf(pm, fmaxf(fmaxf(st[tt][0], st[tt][1]), fmaxf(st[tt][2], st[tt][3])));
      if (!__all(pm <= mreg + 8.f)) {  // slow path: reduce + rescale
        float t0 = pm;
        t0 = fmaxf(t0, __shfl_xor(t0, 16));
        t0 = fmaxf(t0, __shfl_xor(t0, 32));
        float mn = fmaxf(mreg, t0);
        float er = exp2f(mreg - mn);
        mreg = mn;
        ll *= er;
#pragma unroll
        for (int r = 0; r < 4; ++r) {
          float e = __shfl(er, lh * 4 + r);
#pragma unroll
          for (int f = 0; f < 4; ++f) o[f][r] *= e;
        }
      }

      // P = exp2(st - m) -> packed bf16 b64 LDS writes; accumulate row sums
      unsigned short* Pw = Pl[w];
      int rbase = l16 * 64;
      float ps = 0.f;
#pragma unroll
      for (int tt = 0; tt < 4; ++tt) {
        float p0 = exp2f(st[tt][0] - mreg);
        float p1 = exp2f(st[tt][1] - mreg);
        float p2 = exp2f(st[tt][2] - mreg);
        float p3 = exp2f(st[tt][3] - mreg);
        ps += (p0 + p1) + (p2 + p3);
        unsigned lo, hi;
        asm("v_cvt_pk_bf16_f32 %0, %1, %2" : "=v"(lo) : "v"(p0), "v"(p1));
        asm("v_cvt_pk_bf16_f32 %0, %1, %2" : "=v"(hi) : "v"(p2), "v"(p3));
        int c8 = tt * 2 + (lh >> 1);
        int off = rbase + ((c8 ^ sw) << 3) + (lh & 1) * 4;
        *(uint2*)(Pw + off) = make_uint2(lo, hi);
      }
      float rs = ps;
      rs += __shfl_xor(rs, 16);
      rs += __shfl_xor(rs, 32);
      ll += rs;

      // PV: O[row=q(lh*4+r)][col=d(f*16+l16)]
      bf16x8 pf0 = *(const bf16x8*)(Pw + rbase + ((lh ^ sw) * 8));
      bf16x8 pf1 = *(const bf16x8*)(Pw + rbase + (((lh + 4) ^ sw) * 8));
#pragma unroll
      for (int f = 0; f < 4; ++f) {
        const unsigned short* vrow = Vb + (f * 16 + l16) * 64;
        bf16x8 vf0 = *(const bf16x8*)(vrow + ((lh ^ sw) * 8));
        bf16x8 vf1 = *(const bf16x8*)(vrow + (((lh + 4) ^ sw) * 8));
        o[f] = MFMA16(pf0, vf0, o[f]);
        o[f] = MFMA16(pf1, vf1, o[f]);
      }
    }
    __syncthreads();
  }

  unsigned short* op = Og + (size_t)bb * 2048 * 1024 + (size_t)hh * 64;
#pragma unroll
  for (int r = 0; r < 4; ++r) {
    float linv = 1.f / __shfl(ll, lh * 4 + r);
    int row = wqb + lh * 4 + r;
#pragma unroll
    for (int f = 0; f < 4; ++f)
      op[(size_t)row * 1024 + f * 16 + l16] = f32_bf16(o[f][r] * linv);
  }
}

extern "C" void kernel_launch(void* const* d_in, const int* in_sizes, int n_in,
                              void* d_out, int out_size, void* d_ws, size_t ws_size,
                              hipStream_t stream) {
  const float* x    = (const float*)d_in[0];
  const float* Wqkv = (const float*)d_in[1];
  const float* Wout = (const float*)d_in[2];
  float* out = (float*)d_out;

  char* ws = (char*)d_ws;
  unsigned short* xb  = (unsigned short*)(ws);                              // 8 MB
  unsigned short* wqb = (unsigned short*)(ws + (size_t)8 * 1024 * 1024);    // 6 MB
  unsigned short* wob = (unsigned short*)(ws + (size_t)14 * 1024 * 1024);   // 2 MB
  unsigned short* qkv = (unsigned short*)(ws + (size_t)16 * 1024 * 1024);   // 24 MB
  unsigned short* att = (unsigned short*)(ws + (size_t)40 * 1024 * 1024);   // 8 MB

  cvt3_kernel<<<2048, 256, 0, stream>>>(x, 4194304 / 4, Wqkv, 3145728 / 4,
                                        Wout, 1048576 / 4, xb, wqb, wob);

  // QKV projection -> Q,K [bh][s][dk] (Q in exp2-space scale); V^T [bh][dk][s]
  gemm_bt<0><<<dim3(24, 32), 256, 0, stream>>>(xb, wqb, (void*)qkv, 4096, 3072, 1024);

  const unsigned short* Qp  = qkv;
  const unsigned short* Kp  = qkv + 4194304;
  const unsigned short* Vtp = qkv + 8388608;
  attn_kernel<<<1024, 256, 0, stream>>>(Qp, Kp, Vtp, att);

  // output projection -> fp32 out
  gemm_bt<1><<<dim3(8, 32), 256, 0, stream>>>(att, wob, (void*)out, 4096, 1024, 1024);
}

// Round 6
// 125.912 us; speedup vs baseline: 1.1294x; 1.0032x over previous
//
#include <hip/hip_runtime.h>
#include <hip/hip_bf16.h>
#include <stdint.h>

typedef __attribute__((ext_vector_type(8))) __bf16 bf16x8;
typedef __attribute__((ext_vector_type(8))) short  short8;
typedef __attribute__((ext_vector_type(4))) float  f32x4;

#define MFMA16(a, b, c) __builtin_amdgcn_mfma_f32_16x16x32_bf16((a), (b), (c), 0, 0, 0)

__device__ __forceinline__ unsigned short f32_bf16(float f) {
  union { float f; unsigned u; } v; v.f = f;
  unsigned r = v.u + 0x7FFFu + ((v.u >> 16) & 1u);
  return (unsigned short)(r >> 16);
}

// async global->LDS, 16B per lane; LDS dest is wave-uniform base (+lane*16 by HW)
__device__ __forceinline__ void gload16(const unsigned short* g, unsigned short* l) {
  __builtin_amdgcn_global_load_lds(
      (const __attribute__((address_space(1))) unsigned int*)(g),
      (__attribute__((address_space(3))) unsigned int*)(l), 16, 0, 0);
}

// ---------------- fp32 -> bf16 convert (all 3 inputs, one launch) ----------------
__global__ void cvt3_kernel(const float* __restrict__ a, int na4,
                            const float* __restrict__ b, int nb4,
                            const float* __restrict__ c, int nc4,
                            unsigned short* __restrict__ oa,
                            unsigned short* __restrict__ ob,
                            unsigned short* __restrict__ oc) {
  int total = na4 + nb4 + nc4;
  for (int i = blockIdx.x * blockDim.x + threadIdx.x; i < total; i += gridDim.x * blockDim.x) {
    const float* src; unsigned short* dst; int j = i;
    if (j < na4) { src = a; dst = oa; }
    else if (j - na4 < nb4) { j -= na4; src = b; dst = ob; }
    else { j -= na4 + nb4; src = c; dst = oc; }
    float4 v = reinterpret_cast<const float4*>(src)[j];
    ushort4 o4;
    o4.x = f32_bf16(v.x); o4.y = f32_bf16(v.y);
    o4.z = f32_bf16(v.z); o4.w = f32_bf16(v.w);
    reinterpret_cast<ushort4*>(dst)[j] = o4;
  }
}

// ---------------- bf16 GEMM, C = A * B^T (m97 structure) ----------------
// Unified 32KB dynamic LDS: [0,8K)=As, [8K,16K)=Bs, [16K,32K)=extra; epilogue
// reuses all 32KB as 4x 8KB per-wave staging regions.
// MODE 0: Q,K -> [bh][s][64] bf16 (Q scaled log2e/8), V -> transposed [bh][64][s]
// MODE 1: fp32 row-major [M][N], LDS-staged coalesced dwordx4 stores
template <int MODE>
__global__ __launch_bounds__(256) void gemm_bt(const unsigned short* __restrict__ A,
                                               const unsigned short* __restrict__ Bm,
                                               void* __restrict__ Cout,
                                               int M, int N, int K) {
  extern __shared__ unsigned short SM[];  // 32768 bytes
  unsigned short* As = SM;
  unsigned short* Bs = SM + 4096;
  const int tid  = threadIdx.x;
  const int lane = tid & 63;
  const int wid  = tid >> 6;
  const int wr   = wid >> 1, wc = wid & 1;
  const int l16  = lane & 15, lh = lane >> 4;
  const int m0   = blockIdx.y * 128;
  const int n0   = blockIdx.x * 128;

  f32x4 acc[4][4];
#pragma unroll
  for (int mi = 0; mi < 4; ++mi)
#pragma unroll
    for (int ni = 0; ni < 4; ++ni) acc[mi][ni] = 0.f;

  const int c0 = tid, c1 = 256 + tid;
  const unsigned short* a0 = A + (size_t)(m0 + (c0 >> 2)) * K + (c0 & 3) * 8;
  const unsigned short* a1 = A + (size_t)(m0 + (c1 >> 2)) * K + (c1 & 3) * 8;
  const unsigned short* b0 = Bm + (size_t)(n0 + (c0 >> 2)) * K + (c0 & 3) * 8;
  const unsigned short* b1 = Bm + (size_t)(n0 + (c1 >> 2)) * K + (c1 & 3) * 8;
  const int d0 = wid * 64 * 8;
  const int d1 = (256 + wid * 64) * 8;

  for (int k0 = 0; k0 < K; k0 += 32) {
    __syncthreads();
    gload16(a0 + k0, As + d0);
    gload16(a1 + k0, As + d1);
    gload16(b0 + k0, Bs + d0);
    gload16(b1 + k0, Bs + d1);
    __syncthreads();
    bf16x8 af[4], bfr[4];
#pragma unroll
    for (int i = 0; i < 4; ++i) {
      af[i]  = *(const bf16x8*)(As + (wr * 64 + i * 16 + l16) * 32 + lh * 8);
      bfr[i] = *(const bf16x8*)(Bs + (wc * 64 + i * 16 + l16) * 32 + lh * 8);
    }
#pragma unroll
    for (int mi = 0; mi < 4; ++mi)
#pragma unroll
      for (int ni = 0; ni < 4; ++ni)
        acc[mi][ni] = MFMA16(af[mi], bfr[ni], acc[mi][ni]);
  }

  __syncthreads();  // all waves done with As/Bs; reuse whole 32KB for epilogue
  unsigned short* Ep = SM + wid * 4096;  // 8KB per wave

  if (MODE == 0) {
    const int gn0 = n0 + wc * 64;
    const int cc  = gn0 >> 10;
    const int hh2 = (gn0 & 1023) >> 6;
    const int gm0 = m0 + wr * 64;
    const int bb2 = gm0 >> 11;
    const int ss0 = gm0 & 2047;
    const int bh2 = bb2 * 16 + hh2;
    unsigned short* qkv = (unsigned short*)Cout;

    if (cc < 2) {
      // LDS [ss][dk], col XOR'd by lh; scalar writes (2-way max), b128 reads
      const float qsc = (cc == 0) ? 0.18033688f : 1.0f;  // 1/sqrt(64)*log2(e)
#pragma unroll
      for (int mi = 0; mi < 4; ++mi)
#pragma unroll
        for (int ni = 0; ni < 4; ++ni)
#pragma unroll
          for (int r = 0; r < 4; ++r) {
            int row = mi * 16 + lh * 4 + r;
            int col = (ni * 16 + l16) ^ (lh << 3);
            Ep[row * 64 + col] = f32_bf16(acc[mi][ni][r] * qsc);
          }
      unsigned short* qk = qkv + (((size_t)cc * 32 + bh2) * 2048 + ss0) * 64;
#pragma unroll
      for (int it = 0; it < 8; ++it) {
        int ci = it * 64 + lane;
        int row = ci >> 3, c = ci & 7;
        short8 vv = *(const short8*)(Ep + row * 64 + ((c ^ ((row >> 2) & 3)) * 8));
        *(short8*)(qk + (size_t)row * 64 + c * 8) = vv;
      }
    } else {
      // V: LDS [dk][ss], packed b64 writes (cvt_pk), b128 row reads
#pragma unroll
      for (int mi = 0; mi < 4; ++mi)
#pragma unroll
        for (int ni = 0; ni < 4; ++ni) {
          int dk = ni * 16 + l16;
          int ssl = mi * 16 + lh * 4;
          unsigned lo, hi;
          asm("v_cvt_pk_bf16_f32 %0, %1, %2" : "=v"(lo) : "v"(acc[mi][ni][0]), "v"(acc[mi][ni][1]));
          asm("v_cvt_pk_bf16_f32 %0, %1, %2" : "=v"(hi) : "v"(acc[mi][ni][2]), "v"(acc[mi][ni][3]));
          int off = dk * 64 + (ssl ^ ((dk & 7) << 3));
          *(uint2*)(Ep + off) = make_uint2(lo, hi);
        }
      unsigned short* vt = qkv + (size_t)8388608 + (size_t)bh2 * 64 * 2048 + ss0;
#pragma unroll
      for (int it = 0; it < 8; ++it) {
        int ci = it * 64 + lane;
        int dk = ci >> 3, c = ci & 7;
        short8 vv = *(const short8*)(Ep + dk * 64 + ((c ^ (dk & 7)) * 8));
        *(short8*)(vt + (size_t)dk * 2048 + c * 8) = vv;
      }
    }
  } else {
    // fp32 out: two 32-col passes through per-wave 8KB LDS; coalesced dwordx4
    float* C = (float*)Cout;
    float* Ef = (float*)Ep;  // [64][32] f32, col XOR-swizzled by (row&7)<<2
    const int gm0 = m0 + wr * 64;
    const int gn0 = n0 + wc * 64;
#pragma unroll
    for (int p = 0; p < 2; ++p) {
#pragma unroll
      for (int mi = 0; mi < 4; ++mi)
#pragma unroll
        for (int q = 0; q < 2; ++q) {
          int ni = 2 * p + q;
#pragma unroll
          for (int r = 0; r < 4; ++r) {
            int row = mi * 16 + lh * 4 + r;
            int col = (q * 16 + l16) ^ ((row & 7) << 2);
            Ef[row * 32 + col] = acc[mi][ni][r];
          }
        }
      // wave-private region: no barrier needed (lgkm ordering within wave)
#pragma unroll
      for (int it = 0; it < 8; ++it) {
        int ci = it * 64 + lane;
        int row = ci >> 3, c4 = ci & 7;
        float4 vv = *(const float4*)(Ef + row * 32 + ((c4 * 4) ^ ((row & 7) << 2)));
        *(float4*)(&C[(size_t)(gm0 + row) * N + gn0 + p * 32 + c4 * 4]) = vv;
      }
    }
  }
}

// ---------------- causal flash attention (swapped-QK^T, 64q/block) ----------------
// Q: [bh][2048][64] (prescaled log2e/8), K: [bh][2048][64], Vt: [bh][64][2048].
// 4 waves x 16 q-rows, KVBLK=64, 1024 blocks. Balanced qt permutation: each CU's
// 4 resident blocks sum to 66 tiles. setprio(1) around compute. Defer-max, exp2.
__global__ __launch_bounds__(256) void attn_kernel(const unsigned short* __restrict__ Qg,
                                                   const unsigned short* __restrict__ Kg,
                                                   const unsigned short* __restrict__ Vtg,
                                                   unsigned short* __restrict__ Og) {
  __shared__ unsigned short Ks[2][64 * 64];
  __shared__ unsigned short Vs[2][64 * 64];
  __shared__ unsigned short Pl[4][16 * 64];

  const int tid  = threadIdx.x;
  const int lane = tid & 63;
  const int w    = tid >> 6;
  const int l16  = lane & 15, lh = lane >> 4;
  // balanced qt map: rings give per-CU sums of 66 tiles with mixed lengths
  const int j    = blockIdx.x >> 5;
  const int ring = j >> 3, k = j & 7;
  const int qt   = (ring == 0) ? 31 - k : (ring == 1) ? k : (ring == 2) ? 23 - k : 8 + k;
  const int bh   = blockIdx.x & 31;
  const int bb   = bh >> 4, hh = bh & 15;
  const int qb   = qt * 64;
  const int wqb  = qb + w * 16;

  const unsigned short* Qh = Qg + (size_t)bh * (2048 * 64);
  const unsigned short* Kh = Kg + (size_t)bh * (2048 * 64);
  const unsigned short* Vh = Vtg + (size_t)bh * (64 * 2048);

  bf16x8 qf[2];
#pragma unroll
  for (int h2 = 0; h2 < 2; ++h2)
    qf[h2] = *(const bf16x8*)(Qh + (size_t)(wqb + l16) * 64 + h2 * 32 + lh * 8);

  float mreg = 0.f;   // defer-max baseline (scores ~0); slow path handles growth
  float ll   = 0.f;
  f32x4 o[4];
#pragma unroll
  for (int f = 0; f < 4; ++f) o[f] = 0.f;

  // staging: LDS slot sigma holds chunk (r=sigma>>3, h=(sigma&7)^(r&7)) - involutive
  const int sA = tid, sB = tid + 256;
  const int rA = sA >> 3, hA = (sA & 7) ^ (rA & 7);
  const int rB = sB >> 3, hB = (sB & 7) ^ (rB & 7);
  const unsigned short* kSrcA = Kh + rA * 64 + hA * 8;
  const unsigned short* kSrcB = Kh + rB * 64 + hB * 8;
  const unsigned short* vSrcA = Vh + (size_t)rA * 2048 + hA * 8;
  const unsigned short* vSrcB = Vh + (size_t)rB * 2048 + hB * 8;
  const int ldsA = w * 64 * 8;
  const int ldsB = (256 + w * 64) * 8;

  const int sw = l16 & 7;
  const int ntiles = qt + 1;

  gload16(kSrcA, &Ks[0][ldsA]);
  gload16(kSrcB, &Ks[0][ldsB]);
  gload16(vSrcA, &Vs[0][ldsA]);
  gload16(vSrcB, &Vs[0][ldsB]);
  __syncthreads();

  for (int t = 0; t < ntiles; ++t) {
    const int kv0 = t * 64;
    const int cur = t & 1;
    if (t + 1 < ntiles) {
      const int nk = kv0 + 64;
      gload16(kSrcA + (size_t)nk * 64, &Ks[cur ^ 1][ldsA]);
      gload16(kSrcB + (size_t)nk * 64, &Ks[cur ^ 1][ldsB]);
      gload16(vSrcA + nk, &Vs[cur ^ 1][ldsA]);
      gload16(vSrcB + nk, &Vs[cur ^ 1][ldsB]);
    }

    {
      const unsigned short* Kb = Ks[cur];
      const unsigned short* Vb = Vs[cur];
      __builtin_amdgcn_s_setprio(1);

      // S^T[tt]: row = kv (tt*16+lh*4+r), col = q-row (l16)
      f32x4 st[4];
#pragma unroll
      for (int tt = 0; tt < 4; ++tt) {
        const unsigned short* krow = Kb + (tt * 16 + l16) * 64;
        bf16x8 kf0 = *(const bf16x8*)(krow + ((lh ^ sw) * 8));
        bf16x8 kf1 = *(const bf16x8*)(krow + (((lh + 4) ^ sw) * 8));
        f32x4 a = {0.f, 0.f, 0.f, 0.f};
        a = MFMA16(kf0, qf[0], a);
        a = MFMA16(kf1, qf[1], a);
        st[tt] = a;
      }

      if (kv0 + 63 > wqb) {  // causal mask (diag tiles only)
        int qrow = wqb + l16;
#pragma unroll
        for (int tt = 0; tt < 4; ++tt) {
          int kvb = kv0 + tt * 16 + lh * 4;
#pragma unroll
          for (int r = 0; r < 4; ++r)
            if (kvb + r > qrow) st[tt][r] = -__builtin_inff();
        }
      }

      // defer-max: fast path has no shuffles, no rescale
      float pm = fmaxf(fmaxf(st[0][0], st[0][1]), fmaxf(st[0][2], st[0][3]));
#pragma unroll
      for (int tt = 1; tt < 4; ++tt)
        pm = fmaxf(pm, fmaxf(fmaxf(st[tt][0], st[tt][1]), fmaxf(st[tt][2], st[tt][3])));
      if (!__all(pm <= mreg + 8.f)) {  // slow path: reduce + rescale
        float t0 = pm;
        t0 = fmaxf(t0, __shfl_xor(t0, 16));
        t0 = fmaxf(t0, __shfl_xor(t0, 32));
        float mn = fmaxf(mreg, t0);
        float er = exp2f(mreg - mn);
        mreg = mn;
        ll *= er;
#pragma unroll
        for (int r = 0; r < 4; ++r) {
          float e = __shfl(er, lh * 4 + r);
#pragma unroll
          for (int f = 0; f < 4; ++f) o[f][r] *= e;
        }
      }

      // P = exp2(st - m) -> packed bf16 b64 LDS writes; accumulate row sums
      unsigned short* Pw = Pl[w];
      int rbase = l16 * 64;
      float ps = 0.f;
#pragma unroll
      for (int tt = 0; tt < 4; ++tt) {
        float p0 = exp2f(st[tt][0] - mreg);
        float p1 = exp2f(st[tt][1] - mreg);
        float p2 = exp2f(st[tt][2] - mreg);
        float p3 = exp2f(st[tt][3] - mreg);
        ps += (p0 + p1) + (p2 + p3);
        unsigned lo, hi;
        asm("v_cvt_pk_bf16_f32 %0, %1, %2" : "=v"(lo) : "v"(p0), "v"(p1));
        asm("v_cvt_pk_bf16_f32 %0, %1, %2" : "=v"(hi) : "v"(p2), "v"(p3));
        int c8 = tt * 2 + (lh >> 1);
        int off = rbase + ((c8 ^ sw) << 3) + (lh & 1) * 4;
        *(uint2*)(Pw + off) = make_uint2(lo, hi);
      }
      float rs = ps;
      rs += __shfl_xor(rs, 16);
      rs += __shfl_xor(rs, 32);
      ll += rs;

      // PV: O[row=q(lh*4+r)][col=d(f*16+l16)]
      bf16x8 pf0 = *(const bf16x8*)(Pw + rbase + ((lh ^ sw) * 8));
      bf16x8 pf1 = *(const bf16x8*)(Pw + rbase + (((lh + 4) ^ sw) * 8));
#pragma unroll
      for (int f = 0; f < 4; ++f) {
        const unsigned short* vrow = Vb + (f * 16 + l16) * 64;
        bf16x8 vf0 = *(const bf16x8*)(vrow + ((lh ^ sw) * 8));
        bf16x8 vf1 = *(const bf16x8*)(vrow + (((lh + 4) ^ sw) * 8));
        o[f] = MFMA16(pf0, vf0, o[f]);
        o[f] = MFMA16(pf1, vf1, o[f]);
      }
      __builtin_amdgcn_s_setprio(0);
    }
    __syncthreads();
  }

  unsigned short* op = Og + (size_t)bb * 2048 * 1024 + (size_t)hh * 64;
#pragma unroll
  for (int r = 0; r < 4; ++r) {
    float linv = 1.f / __shfl(ll, lh * 4 + r);
    int row = wqb + lh * 4 + r;
#pragma unroll
    for (int f = 0; f < 4; ++f)
      op[(size_t)row * 1024 + f * 16 + l16] = f32_bf16(o[f][r] * linv);
  }
}

extern "C" void kernel_launch(void* const* d_in, const int* in_sizes, int n_in,
                              void* d_out, int out_size, void* d_ws, size_t ws_size,
                              hipStream_t stream) {
  const float* x    = (const float*)d_in[0];
  const float* Wqkv = (const float*)d_in[1];
  const float* Wout = (const float*)d_in[2];
  float* out = (float*)d_out;

  char* ws = (char*)d_ws;
  unsigned short* xb  = (unsigned short*)(ws);                              // 8 MB
  unsigned short* wqb = (unsigned short*)(ws + (size_t)8 * 1024 * 1024);    // 6 MB
  unsigned short* wob = (unsigned short*)(ws + (size_t)14 * 1024 * 1024);   // 2 MB
  unsigned short* qkv = (unsigned short*)(ws + (size_t)16 * 1024 * 1024);   // 24 MB
  unsigned short* att = (unsigned short*)(ws + (size_t)40 * 1024 * 1024);   // 8 MB

  cvt3_kernel<<<2048, 256, 0, stream>>>(x, 4194304 / 4, Wqkv, 3145728 / 4,
                                        Wout, 1048576 / 4, xb, wqb, wob);

  // QKV projection -> Q,K [bh][s][dk] (Q in exp2-space scale); V^T [bh][dk][s]
  gemm_bt<0><<<dim3(24, 32), 256, 32768, stream>>>(xb, wqb, (void*)qkv, 4096, 3072, 1024);

  const unsigned short* Qp  = qkv;
  const unsigned short* Kp  = qkv + 4194304;
  const unsigned short* Vtp = qkv + 8388608;
  attn_kernel<<<1024, 256, 0, stream>>>(Qp, Kp, Vtp, att);

  // output projection -> fp32 out
  gemm_bt<1><<<dim3(8, 32), 256, 32768, stream>>>(att, wob, (void*)out, 4096, 1024, 1024);
}

// Round 7
// 117.982 us; speedup vs baseline: 1.2053x; 1.0672x over previous
//
#include <hip/hip_runtime.h>
#include <hip/hip_bf16.h>
#include <stdint.h>

typedef __attribute__((ext_vector_type(8))) __bf16 bf16x8;
typedef __attribute__((ext_vector_type(8))) short  short8;
typedef __attribute__((ext_vector_type(4))) float  f32x4;

#define MFMA16(a, b, c) __builtin_amdgcn_mfma_f32_16x16x32_bf16((a), (b), (c), 0, 0, 0)

__device__ __forceinline__ unsigned short f32_bf16(float f) {
  union { float f; unsigned u; } v; v.f = f;
  unsigned r = v.u + 0x7FFFu + ((v.u >> 16) & 1u);
  return (unsigned short)(r >> 16);
}

// async global->LDS, 16B per lane; LDS dest is wave-uniform base (+lane*16 by HW)
__device__ __forceinline__ void gload16(const unsigned short* g, unsigned short* l) {
  __builtin_amdgcn_global_load_lds(
      (const __attribute__((address_space(1))) unsigned int*)(g),
      (__attribute__((address_space(3))) unsigned int*)(l), 16, 0, 0);
}

// ---------------- fp32 -> bf16 convert (all 3 inputs, one launch) ----------------
__global__ void cvt3_kernel(const float* __restrict__ a, int na4,
                            const float* __restrict__ b, int nb4,
                            const float* __restrict__ c, int nc4,
                            unsigned short* __restrict__ oa,
                            unsigned short* __restrict__ ob,
                            unsigned short* __restrict__ oc) {
  int total = na4 + nb4 + nc4;
  for (int i = blockIdx.x * blockDim.x + threadIdx.x; i < total; i += gridDim.x * blockDim.x) {
    const float* src; unsigned short* dst; int j = i;
    if (j < na4) { src = a; dst = oa; }
    else if (j - na4 < nb4) { j -= na4; src = b; dst = ob; }
    else { j -= na4 + nb4; src = c; dst = oc; }
    float4 v = reinterpret_cast<const float4*>(src)[j];
    ushort4 o4;
    o4.x = f32_bf16(v.x); o4.y = f32_bf16(v.y);
    o4.z = f32_bf16(v.z); o4.w = f32_bf16(v.w);
    reinterpret_cast<ushort4*>(dst)[j] = o4;
  }
}

// ---------------- QKV GEMM: 256x256 8-phase (T3+T4+T5), BK=64 ----------------
// A: xb [4096][1024] bf16, Bm: Wqkv [3072][1024] bf16. M=4096 N=3072 K=1024.
// 512 thr = 8 waves (2M x 4N); per-wave C = 128x64. LDS 128KB dynamic:
// buf b: A at b*32768+half*8192, B at b*32768+16384+half*8192 (elems).
// Half-stage = 16KB = 2 gload16/thread. Schedule per tile U (4 phases):
//   p1: ds bf[0..3][0..1]+af[0,1]; stage A0(U+1); bar; 16 MFMA; bar
//   p2: ds af[2,3];                stage A1(U+1); bar; 16 MFMA; bar
//   p3: ds af[4,5];                stage B0(U+2); bar; 16 MFMA; bar
//   p4: ds af[6,7];                stage B1(U+2); bar; 16 MFMA; vmcnt(4); bar
// vmcnt(4) leaves only B0,B1(U+2) in flight => A(U+1),B(U+1) landed. Never 0.
// Raw s_barrier only (no __syncthreads: it drains vmcnt and kills the pipeline).
__global__ __launch_bounds__(512, 2) void gemm_qkv_8ph(const unsigned short* __restrict__ A,
                                                       const unsigned short* __restrict__ Bm,
                                                       unsigned short* __restrict__ qkv) {
  extern __shared__ unsigned short SM[];  // 65536 elems = 131072 B
  const int tid  = threadIdx.x;
  const int lane = tid & 63;
  const int w    = tid >> 6;          // 0..7
  const int wr   = w >> 2, wc = w & 3;
  const int l16  = lane & 15, lh = lane >> 4;
  const int sw   = l16 & 7;
  const int m0   = blockIdx.y * 256;
  const int n0   = blockIdx.x * 256;

  f32x4 acc[8][4];
#pragma unroll
  for (int mi = 0; mi < 8; ++mi)
#pragma unroll
    for (int ni = 0; ni < 4; ++ni) acc[mi][ni] = 0.f;

  // staging: half = 128 rows x 64 k = 1024 chunks of 16B; thread covers slots tid, tid+512
  // slot s holds content chunk: r = s>>3, hc = (s&7)^(r&7)  (involutive swizzle)
  const int r0 = tid >> 3,         h0 = (tid & 7) ^ (r0 & 7);
  const int r1 = (tid + 512) >> 3, h1 = (tid & 7) ^ (r1 & 7);  // (tid+512)&7 == tid&7
  const unsigned short* Asrc[2][2];
  const unsigned short* Bsrc[2][2];
  Asrc[0][0] = A + (size_t)(m0 + r0) * 1024 + h0 * 8;
  Asrc[0][1] = A + (size_t)(m0 + r1) * 1024 + h1 * 8;
  Asrc[1][0] = A + (size_t)(m0 + 128 + r0) * 1024 + h0 * 8;
  Asrc[1][1] = A + (size_t)(m0 + 128 + r1) * 1024 + h1 * 8;
  Bsrc[0][0] = Bm + (size_t)(n0 + r0) * 1024 + h0 * 8;
  Bsrc[0][1] = Bm + (size_t)(n0 + r1) * 1024 + h1 * 8;
  Bsrc[1][0] = Bm + (size_t)(n0 + 128 + r0) * 1024 + h0 * 8;
  Bsrc[1][1] = Bm + (size_t)(n0 + 128 + r1) * 1024 + h1 * 8;
  const int ld0 = (w * 64) * 8;          // wave-uniform LDS elem offsets
  const int ld1 = (512 + w * 64) * 8;

#define STAGE_A(buf, h, U) do { \
    gload16(Asrc[h][0] + (U) * 64, SM + (buf) * 32768 + (h) * 8192 + ld0); \
    gload16(Asrc[h][1] + (U) * 64, SM + (buf) * 32768 + (h) * 8192 + ld1); } while (0)
#define STAGE_B(buf, h, U) do { \
    gload16(Bsrc[h][0] + (U) * 64, SM + (buf) * 32768 + 16384 + (h) * 8192 + ld0); \
    gload16(Bsrc[h][1] + (U) * 64, SM + (buf) * 32768 + 16384 + (h) * 8192 + ld1); } while (0)

  // prologue: tile0 A+B, tile1 B; then wait all but the 2 newest half-stages
  STAGE_A(0, 0, 0); STAGE_A(0, 1, 0);
  STAGE_B(0, 0, 0); STAGE_B(0, 1, 0);
  STAGE_B(1, 0, 1); STAGE_B(1, 1, 1);
  asm volatile("s_waitcnt vmcnt(4)" ::: "memory");
  __builtin_amdgcn_s_barrier();

  const int NT = 16;  // K/64
#pragma unroll 2
  for (int U = 0; U < NT; ++U) {
    const int b = U & 1;
    const unsigned short* Ab = SM + b * 32768 + wr * 8192;
    const unsigned short* Bb = SM + b * 32768 + 16384 + (wc >> 1) * 8192;
    const int rB = (wc & 1) * 64;
    bf16x8 bfr[4][2], af[2][2];

#define LDA(i, j) (*(const bf16x8*)(Ab + (((i) * 16 + l16) * 8 + (((j) * 4 + lh) ^ sw)) * 8))
#define LDB(n, j) (*(const bf16x8*)(Bb + (((rB + (n) * 16 + l16)) * 8 + (((j) * 4 + lh) ^ sw)) * 8))
#define PHASE_MFMA(p) \
    __builtin_amdgcn_s_setprio(1); \
    _Pragma("unroll") \
    for (int n = 0; n < 4; ++n) { \
      acc[2*(p)][n]   = MFMA16(af[0][0], bfr[n][0], acc[2*(p)][n]); \
      acc[2*(p)][n]   = MFMA16(af[0][1], bfr[n][1], acc[2*(p)][n]); \
      acc[2*(p)+1][n] = MFMA16(af[1][0], bfr[n][0], acc[2*(p)+1][n]); \
      acc[2*(p)+1][n] = MFMA16(af[1][1], bfr[n][1], acc[2*(p)+1][n]); \
    } \
    __builtin_amdgcn_s_setprio(0);

    // ---- phase 1 ----
    af[0][0] = LDA(0, 0); af[0][1] = LDA(0, 1);
    af[1][0] = LDA(1, 0); af[1][1] = LDA(1, 1);
#pragma unroll
    for (int n = 0; n < 4; ++n) { bfr[n][0] = LDB(n, 0); bfr[n][1] = LDB(n, 1); }
    if (U + 1 < NT) STAGE_A(b ^ 1, 0, U + 1);
    __builtin_amdgcn_s_barrier();
    PHASE_MFMA(0)
    __builtin_amdgcn_s_barrier();
    // ---- phase 2 ----
    af[0][0] = LDA(2, 0); af[0][1] = LDA(2, 1);
    af[1][0] = LDA(3, 0); af[1][1] = LDA(3, 1);
    if (U + 1 < NT) STAGE_A(b ^ 1, 1, U + 1);
    __builtin_amdgcn_s_barrier();
    PHASE_MFMA(1)
    __builtin_amdgcn_s_barrier();
    // ---- phase 3 ----
    af[0][0] = LDA(4, 0); af[0][1] = LDA(4, 1);
    af[1][0] = LDA(5, 0); af[1][1] = LDA(5, 1);
    if (U + 2 < NT) STAGE_B(b, 0, U + 2);
    __builtin_amdgcn_s_barrier();
    PHASE_MFMA(2)
    __builtin_amdgcn_s_barrier();
    // ---- phase 4 ----
    af[0][0] = LDA(6, 0); af[0][1] = LDA(6, 1);
    af[1][0] = LDA(7, 0); af[1][1] = LDA(7, 1);
    if (U + 2 < NT) STAGE_B(b, 1, U + 2);
    __builtin_amdgcn_s_barrier();
    PHASE_MFMA(3)
    asm volatile("s_waitcnt vmcnt(4)" ::: "memory");
    __builtin_amdgcn_s_barrier();
#undef LDA
#undef LDB
#undef PHASE_MFMA
  }

  __syncthreads();  // pipeline drained; reuse all 128KB as per-wave epilogue staging
  unsigned short* Ep = SM + w * 8192;  // 16KB per wave
  const int gn0 = n0 + wc * 64;
  const int cc  = gn0 >> 10;
  const int hh2 = (gn0 & 1023) >> 6;
  const int gm0 = m0 + wr * 128;
  const int bb2 = gm0 >> 11;
  const int ss0 = gm0 & 2047;
  const int bh2 = bb2 * 16 + hh2;

  if (cc < 2) {
    // Q/K: LDS [ss 128][dk 64], col XOR by writer-lh; b128 reads, coalesced stores
    const float qsc = (cc == 0) ? 0.18033688f : 1.0f;  // 1/sqrt(64)*log2(e)
#pragma unroll
    for (int mi = 0; mi < 8; ++mi)
#pragma unroll
      for (int ni = 0; ni < 4; ++ni)
#pragma unroll
        for (int r = 0; r < 4; ++r) {
          int row = mi * 16 + lh * 4 + r;
          int col = (ni * 16 + l16) ^ (lh << 3);
          Ep[row * 64 + col] = f32_bf16(acc[mi][ni][r] * qsc);
        }
    unsigned short* qk = qkv + (((size_t)cc * 32 + bh2) * 2048 + ss0) * 64;
#pragma unroll
    for (int it = 0; it < 16; ++it) {
      int ci = it * 64 + lane;
      int row = ci >> 3, c = ci & 7;
      short8 vv = *(const short8*)(Ep + row * 64 + ((c ^ ((row >> 2) & 3)) * 8));
      *(short8*)(qk + (size_t)row * 64 + c * 8) = vv;
    }
  } else {
    // V: LDS [dk 64][ss 128], packed b64 writes, b128 row reads -> V^T [bh][dk][s]
#pragma unroll
    for (int mi = 0; mi < 8; ++mi)
#pragma unroll
      for (int ni = 0; ni < 4; ++ni) {
        int dk = ni * 16 + l16;
        int ssl = mi * 16 + lh * 4;
        unsigned lo, hi;
        asm("v_cvt_pk_bf16_f32 %0, %1, %2" : "=v"(lo) : "v"(acc[mi][ni][0]), "v"(acc[mi][ni][1]));
        asm("v_cvt_pk_bf16_f32 %0, %1, %2" : "=v"(hi) : "v"(acc[mi][ni][2]), "v"(acc[mi][ni][3]));
        int off = dk * 128 + (ssl ^ ((dk & 7) << 3));
        *(uint2*)(Ep + off) = make_uint2(lo, hi);
      }
    unsigned short* vt = qkv + (size_t)8388608 + (size_t)bh2 * 64 * 2048 + ss0;
#pragma unroll
    for (int it = 0; it < 16; ++it) {
      int ci = it * 64 + lane;
      int dk = ci >> 4, c = ci & 15;
      short8 vv = *(const short8*)(Ep + dk * 128 + ((c ^ (dk & 7)) * 8));
      *(short8*)(vt + (size_t)dk * 2048 + c * 8) = vv;
    }
  }
#undef STAGE_A
#undef STAGE_B
}

// ---------------- out-proj GEMM, C = A * B^T (m97 128^2 structure) ----------------
__global__ __launch_bounds__(256) void gemm_out(const unsigned short* __restrict__ A,
                                                const unsigned short* __restrict__ Bm,
                                                float* __restrict__ C,
                                                int M, int N, int K) {
  extern __shared__ unsigned short SM[];  // 32768 bytes
  unsigned short* As = SM;
  unsigned short* Bs = SM + 4096;
  const int tid  = threadIdx.x;
  const int lane = tid & 63;
  const int wid  = tid >> 6;
  const int wr   = wid >> 1, wc = wid & 1;
  const int l16  = lane & 15, lh = lane >> 4;
  const int m0   = blockIdx.y * 128;
  const int n0   = blockIdx.x * 128;

  f32x4 acc[4][4];
#pragma unroll
  for (int mi = 0; mi < 4; ++mi)
#pragma unroll
    for (int ni = 0; ni < 4; ++ni) acc[mi][ni] = 0.f;

  const int c0 = tid, c1 = 256 + tid;
  const unsigned short* a0 = A + (size_t)(m0 + (c0 >> 2)) * K + (c0 & 3) * 8;
  const unsigned short* a1 = A + (size_t)(m0 + (c1 >> 2)) * K + (c1 & 3) * 8;
  const unsigned short* b0 = Bm + (size_t)(n0 + (c0 >> 2)) * K + (c0 & 3) * 8;
  const unsigned short* b1 = Bm + (size_t)(n0 + (c1 >> 2)) * K + (c1 & 3) * 8;
  const int d0 = wid * 64 * 8;
  const int d1 = (256 + wid * 64) * 8;

  for (int k0 = 0; k0 < K; k0 += 32) {
    __syncthreads();
    gload16(a0 + k0, As + d0);
    gload16(a1 + k0, As + d1);
    gload16(b0 + k0, Bs + d0);
    gload16(b1 + k0, Bs + d1);
    __syncthreads();
    bf16x8 af[4], bfr[4];
#pragma unroll
    for (int i = 0; i < 4; ++i) {
      af[i]  = *(const bf16x8*)(As + (wr * 64 + i * 16 + l16) * 32 + lh * 8);
      bfr[i] = *(const bf16x8*)(Bs + (wc * 64 + i * 16 + l16) * 32 + lh * 8);
    }
#pragma unroll
    for (int mi = 0; mi < 4; ++mi)
#pragma unroll
      for (int ni = 0; ni < 4; ++ni)
        acc[mi][ni] = MFMA16(af[mi], bfr[ni], acc[mi][ni]);
  }

  __syncthreads();
  float* Ef = (float*)(SM + wid * 4096);  // per-wave 8KB: [64][32] f32, col XOR
  const int gm0 = m0 + wr * 64;
  const int gn0 = n0 + wc * 64;
#pragma unroll
  for (int p = 0; p < 2; ++p) {
#pragma unroll
    for (int mi = 0; mi < 4; ++mi)
#pragma unroll
      for (int q = 0; q < 2; ++q) {
        int ni = 2 * p + q;
#pragma unroll
        for (int r = 0; r < 4; ++r) {
          int row = mi * 16 + lh * 4 + r;
          int col = (q * 16 + l16) ^ ((row & 7) << 2);
          Ef[row * 32 + col] = acc[mi][ni][r];
        }
      }
#pragma unroll
    for (int it = 0; it < 8; ++it) {
      int ci = it * 64 + lane;
      int row = ci >> 3, c4 = ci & 7;
      float4 vv = *(const float4*)(Ef + row * 32 + ((c4 * 4) ^ ((row & 7) << 2)));
      *(float4*)(&C[(size_t)(gm0 + row) * N + gn0 + p * 32 + c4 * 4]) = vv;
    }
  }
}

// ---------------- causal flash attention (swapped-QK^T, 64q/block) ----------------
__global__ __launch_bounds__(256) void attn_kernel(const unsigned short* __restrict__ Qg,
                                                   const unsigned short* __restrict__ Kg,
                                                   const unsigned short* __restrict__ Vtg,
                                                   unsigned short* __restrict__ Og) {
  __shared__ unsigned short Ks[2][64 * 64];
  __shared__ unsigned short Vs[2][64 * 64];
  __shared__ unsigned short Pl[4][16 * 64];

  const int tid  = threadIdx.x;
  const int lane = tid & 63;
  const int w    = tid >> 6;
  const int l16  = lane & 15, lh = lane >> 4;
  const int j    = blockIdx.x >> 5;
  const int ring = j >> 3, k = j & 7;
  const int qt   = (ring == 0) ? 31 - k : (ring == 1) ? k : (ring == 2) ? 23 - k : 8 + k;
  const int bh   = blockIdx.x & 31;
  const int bb   = bh >> 4, hh = bh & 15;
  const int qb   = qt * 64;
  const int wqb  = qb + w * 16;

  const unsigned short* Qh = Qg + (size_t)bh * (2048 * 64);
  const unsigned short* Kh = Kg + (size_t)bh * (2048 * 64);
  const unsigned short* Vh = Vtg + (size_t)bh * (64 * 2048);

  bf16x8 qf[2];
#pragma unroll
  for (int h2 = 0; h2 < 2; ++h2)
    qf[h2] = *(const bf16x8*)(Qh + (size_t)(wqb + l16) * 64 + h2 * 32 + lh * 8);

  float mreg = 0.f;
  float ll   = 0.f;
  f32x4 o[4];
#pragma unroll
  for (int f = 0; f < 4; ++f) o[f] = 0.f;

  const int sA = tid, sB = tid + 256;
  const int rA = sA >> 3, hA = (sA & 7) ^ (rA & 7);
  const int rB = sB >> 3, hB = (sB & 7) ^ (rB & 7);
  const unsigned short* kSrcA = Kh + rA * 64 + hA * 8;
  const unsigned short* kSrcB = Kh + rB * 64 + hB * 8;
  const unsigned short* vSrcA = Vh + (size_t)rA * 2048 + hA * 8;
  const unsigned short* vSrcB = Vh + (size_t)rB * 2048 + hB * 8;
  const int ldsA = w * 64 * 8;
  const int ldsB = (256 + w * 64) * 8;

  const int sw = l16 & 7;
  const int ntiles = qt + 1;

  gload16(kSrcA, &Ks[0][ldsA]);
  gload16(kSrcB, &Ks[0][ldsB]);
  gload16(vSrcA, &Vs[0][ldsA]);
  gload16(vSrcB, &Vs[0][ldsB]);
  __syncthreads();

  for (int t = 0; t < ntiles; ++t) {
    const int kv0 = t * 64;
    const int cur = t & 1;
    if (t + 1 < ntiles) {
      const int nk = kv0 + 64;
      gload16(kSrcA + (size_t)nk * 64, &Ks[cur ^ 1][ldsA]);
      gload16(kSrcB + (size_t)nk * 64, &Ks[cur ^ 1][ldsB]);
      gload16(vSrcA + nk, &Vs[cur ^ 1][ldsA]);
      gload16(vSrcB + nk, &Vs[cur ^ 1][ldsB]);
    }

    {
      const unsigned short* Kb = Ks[cur];
      const unsigned short* Vb = Vs[cur];
      __builtin_amdgcn_s_setprio(1);

      f32x4 st[4];
#pragma unroll
      for (int tt = 0; tt < 4; ++tt) {
        const unsigned short* krow = Kb + (tt * 16 + l16) * 64;
        bf16x8 kf0 = *(const bf16x8*)(krow + ((lh ^ sw) * 8));
        bf16x8 kf1 = *(const bf16x8*)(krow + (((lh + 4) ^ sw) * 8));
        f32x4 a = {0.f, 0.f, 0.f, 0.f};
        a = MFMA16(kf0, qf[0], a);
        a = MFMA16(kf1, qf[1], a);
        st[tt] = a;
      }

      if (kv0 + 63 > wqb) {
        int qrow = wqb + l16;
#pragma unroll
        for (int tt = 0; tt < 4; ++tt) {
          int kvb = kv0 + tt * 16 + lh * 4;
#pragma unroll
          for (int r = 0; r < 4; ++r)
            if (kvb + r > qrow) st[tt][r] = -__builtin_inff();
        }
      }

      float pm = fmaxf(fmaxf(st[0][0], st[0][1]), fmaxf(st[0][2], st[0][3]));
#pragma unroll
      for (int tt = 1; tt < 4; ++tt)
        pm = fmaxf(pm, fmaxf(fmaxf(st[tt][0], st[tt][1]), fmaxf(st[tt][2], st[tt][3])));
      if (!__all(pm <= mreg + 8.f)) {
        float t0 = pm;
        t0 = fmaxf(t0, __shfl_xor(t0, 16));
        t0 = fmaxf(t0, __shfl_xor(t0, 32));
        float mn = fmaxf(mreg, t0);
        float er = exp2f(mreg - mn);
        mreg = mn;
        ll *= er;
#pragma unroll
        for (int r = 0; r < 4; ++r) {
          float e = __shfl(er, lh * 4 + r);
#pragma unroll
          for (int f = 0; f < 4; ++f) o[f][r] *= e;
        }
      }

      unsigned short* Pw = Pl[w];
      int rbase = l16 * 64;
      float ps = 0.f;
#pragma unroll
      for (int tt = 0; tt < 4; ++tt) {
        float p0 = exp2f(st[tt][0] - mreg);
        float p1 = exp2f(st[tt][1] - mreg);
        float p2 = exp2f(st[tt][2] - mreg);
        float p3 = exp2f(st[tt][3] - mreg);
        ps += (p0 + p1) + (p2 + p3);
        unsigned lo, hi;
        asm("v_cvt_pk_bf16_f32 %0, %1, %2" : "=v"(lo) : "v"(p0), "v"(p1));
        asm("v_cvt_pk_bf16_f32 %0, %1, %2" : "=v"(hi) : "v"(p2), "v"(p3));
        int c8 = tt * 2 + (lh >> 1);
        int off = rbase + ((c8 ^ sw) << 3) + (lh & 1) * 4;
        *(uint2*)(Pw + off) = make_uint2(lo, hi);
      }
      float rs = ps;
      rs += __shfl_xor(rs, 16);
      rs += __shfl_xor(rs, 32);
      ll += rs;

      bf16x8 pf0 = *(const bf16x8*)(Pw + rbase + ((lh ^ sw) * 8));
      bf16x8 pf1 = *(const bf16x8*)(Pw + rbase + (((lh + 4) ^ sw) * 8));
#pragma unroll
      for (int f = 0; f < 4; ++f) {
        const unsigned short* vrow = Vb + (f * 16 + l16) * 64;
        bf16x8 vf0 = *(const bf16x8*)(vrow + ((lh ^ sw) * 8));
        bf16x8 vf1 = *(const bf16x8*)(vrow + (((lh + 4) ^ sw) * 8));
        o[f] = MFMA16(pf0, vf0, o[f]);
        o[f] = MFMA16(pf1, vf1, o[f]);
      }
      __builtin_amdgcn_s_setprio(0);
    }
    __syncthreads();
  }

  unsigned short* op = Og + (size_t)bb * 2048 * 1024 + (size_t)hh * 64;
#pragma unroll
  for (int r = 0; r < 4; ++r) {
    float linv = 1.f / __shfl(ll, lh * 4 + r);
    int row = wqb + lh * 4 + r;
#pragma unroll
    for (int f = 0; f < 4; ++f)
      op[(size_t)row * 1024 + f * 16 + l16] = f32_bf16(o[f][r] * linv);
  }
}

extern "C" void kernel_launch(void* const* d_in, const int* in_sizes, int n_in,
                              void* d_out, int out_size, void* d_ws, size_t ws_size,
                              hipStream_t stream) {
  const float* x    = (const float*)d_in[0];
  const float* Wqkv = (const float*)d_in[1];
  const float* Wout = (const float*)d_in[2];
  float* out = (float*)d_out;

  char* ws = (char*)d_ws;
  unsigned short* xb  = (unsigned short*)(ws);                              // 8 MB
  unsigned short* wqb = (unsigned short*)(ws + (size_t)8 * 1024 * 1024);    // 6 MB
  unsigned short* wob = (unsigned short*)(ws + (size_t)14 * 1024 * 1024);   // 2 MB
  unsigned short* qkv = (unsigned short*)(ws + (size_t)16 * 1024 * 1024);   // 24 MB
  unsigned short* att = (unsigned short*)(ws + (size_t)40 * 1024 * 1024);   // 8 MB

  static bool attr_set = false;
  if (!attr_set) {
    hipFuncSetAttribute((const void*)gemm_qkv_8ph,
                        hipFuncAttributeMaxDynamicSharedMemorySize, 131072);
    attr_set = true;
  }

  cvt3_kernel<<<2048, 256, 0, stream>>>(x, 4194304 / 4, Wqkv, 3145728 / 4,
                                        Wout, 1048576 / 4, xb, wqb, wob);

  // QKV projection (8-phase 256^2) -> Q,K [bh][s][dk] (Q exp2-scaled); V^T [bh][dk][s]
  gemm_qkv_8ph<<<dim3(12, 16), 512, 131072, stream>>>(xb, wqb, qkv);

  const unsigned short* Qp  = qkv;
  const unsigned short* Kp  = qkv + 4194304;
  const unsigned short* Vtp = qkv + 8388608;
  attn_kernel<<<1024, 256, 0, stream>>>(Qp, Kp, Vtp, att);

  // output projection -> fp32 out
  gemm_out<<<dim3(8, 32), 256, 32768, stream>>>(att, wob, out, 4096, 1024, 1024);
}